// Round 20
// baseline (1052.694 us; speedup 1.0000x reference)
//
#include <hip/hip_runtime.h>
#include <hip/hip_bf16.h>
#include <math.h>

#define NNODES 16000
#define NEDGES 256000

typedef float v2f __attribute__((ext_vector_type(2)));
typedef short bf16x8 __attribute__((ext_vector_type(8)));
typedef float f32x4 __attribute__((ext_vector_type(4)));

// ---------------- ws layout (float element offsets) ----------------
#define WS_CG   0
#define WS_Y0   512
#define WS_Y1   (WS_Y0 + NNODES*64)
#define WS_SC0  (WS_Y1 + NNODES*192)
#define WS_SC1  (WS_SC0 + NNODES*64)
#define WS_BIG  (WS_SC1 + NNODES*192)
#define WS_AGG  WS_BIG
#define WS_X0N  (WS_BIG + NNODES*9*64)
#define WS_X1N  (WS_X0N + NNODES*64)
#define WS_CSR  (WS_BIG + NNODES*21*64)   // int region: counts|off|cursor|eidx
#define WS_WPK  (WS_CSR + 310000)         // MFMA-packed MLP weights (bf16, 36864)
#define WS_WLPK (WS_WPK + 18432)          // MFMA-packed lin weights (bf16, <=28672)
#define WS_WBUF (WS_WLPK + 14336)         // per-edge TP-weight buffer (bf16, chunked)
// A is written IN PLACE over Agg rows 0..8 per node (k_lin).

// CG dense storage offsets for PATHS_P (l1,l2,l3):
// p0 (0,0,0) off 0   | p1 (0,1,1) off 1  | p2 (0,2,2) off 10 | p3 (1,0,1) off 35
// p4 (1,1,0) off 44  | p5 (1,1,2) off 53 | p6 (1,2,1) off 98 | p7 (2,0,2) off 143
// p8 (2,1,1) off 168 | p9 (2,2,0) off 213| p10(2,2,2) off 238  -> total 363

__device__ __forceinline__ float silu_f(float x) { return x / (1.f + expf(-x)); }
__device__ __forceinline__ short f2bs(float x) {
  __hip_bfloat16 h = __float2bfloat16(x);
  return *reinterpret_cast<short*>(&h);
}
__device__ __forceinline__ bf16x8 cvt8(const float* p) {
  float4 a = *(const float4*)p, b = *(const float4*)(p + 4);
  bf16x8 r;
  r[0]=f2bs(a.x); r[1]=f2bs(a.y); r[2]=f2bs(a.z); r[3]=f2bs(a.w);
  r[4]=f2bs(b.x); r[5]=f2bs(b.y); r[6]=f2bs(b.z); r[7]=f2bs(b.w);
  return r;
}

// ================= CG init: LDS-parallel, one 512-thread block =================
__device__ __forceinline__ void c2r_elem(int l, int r, int c, double& re, double& im) {
  re = 0.0; im = 0.0;
  int mr = r - l, mc = c - l;
  const double s = 0.70710678118654752440;
  if (mr == 0) { if (mc == 0) re = 1.0; return; }
  if (mr > 0) {
    double sg = (mr & 1) ? -1.0 : 1.0;
    if (mc == mr) re = sg * s;
    else if (mc == -mr) re = s;
  } else {
    int m = -mr;
    double sg = (m & 1) ? -1.0 : 1.0;
    if (mc == m) im = -sg * s;
    else if (mc == -m) im = s;
  }
}

__constant__ int CG_L1[11] = {0,0,0,1,1,1,1,2,2,2,2};
__constant__ int CG_L2[11] = {0,1,2,0,1,1,2,0,1,2,2};
__constant__ int CG_L3[11] = {0,1,2,1,0,2,1,2,1,0,2};
__constant__ int CG_OFF[11] = {0,1,10,35,44,53,98,143,168,213,238};
__constant__ double CG_FACT[8] = {1.,1.,2.,6.,24.,120.,720.,5040.};

__launch_bounds__(512)
__global__ void k_cg(float* __restrict__ cg) {
  __shared__ double CCs[11][125];
  __shared__ double trs[11*125];
  __shared__ double tis[11*125];
  __shared__ double scaleL[11];
  __shared__ int useRL[11];
  int tid = threadIdx.x;

  for (int i = tid; i < 11*125; i += 512) CCs[i/125][i%125] = 0.0;
  __syncthreads();

  for (int idx = tid; idx < 11*25; idx += 512) {
    int p = idx / 25, r = idx % 25;
    int i1 = r / 5, i2 = r % 5;
    int l1 = CG_L1[p], l2 = CG_L2[p], l3 = CG_L3[p];
    int d2 = 2*l2+1, d3 = 2*l3+1;
    if (i1 >= 2*l1+1 || i2 >= d2) continue;
    int m1 = i1 - l1, m2 = i2 - l2, m3 = m1 + m2;
    if (m3 < -l3 || m3 > l3) continue;
    double pre0 = sqrt((double)(2*l3+1) * CG_FACT[l3+l1-l2] * CG_FACT[l3-l1+l2]
                       * CG_FACT[l1+l2-l3] / CG_FACT[l1+l2+l3+1]);
    double pre = pre0 * sqrt(CG_FACT[l3+m3]*CG_FACT[l3-m3]*CG_FACT[l1-m1]
                             *CG_FACT[l1+m1]*CG_FACT[l2-m2]*CG_FACT[l2+m2]);
    double ssum = 0.0;
    for (int k = 0; k <= l1 + l2 - l3; k++) {
      int a2 = l1-m1-k, a3 = l2+m2-k, a4 = l3-l2+m1+k, a5 = l3-l1-m2+k;
      if (a2 < 0 || a3 < 0 || a4 < 0 || a5 < 0) continue;
      double den = CG_FACT[k]*CG_FACT[l1+l2-l3-k]*CG_FACT[a2]*CG_FACT[a3]*CG_FACT[a4]*CG_FACT[a5];
      ssum += ((k & 1) ? -1.0 : 1.0) / den;
    }
    CCs[p][(i1*d2 + i2)*d3 + (m3 + l3)] = pre * ssum;
  }
  __syncthreads();

  for (int idx = tid; idx < 11*125; idx += 512) {
    int p = idx / 125, r = idx % 125;
    int a = r / 25, b = (r / 5) % 5, c = r % 5;
    int l1 = CG_L1[p], l2 = CG_L2[p], l3 = CG_L3[p];
    int d1 = 2*l1+1, d2 = 2*l2+1, d3 = 2*l3+1;
    if (a >= d1 || b >= d2 || c >= d3) continue;
    double tr = 0.0, ti = 0.0;
    for (int i = 0; i < d1; i++) for (int j = 0; j < d2; j++) {
      double a1r, a1i, a2r, a2i;
      c2r_elem(l1, a, i, a1r, a1i); a1i = -a1i;
      c2r_elem(l2, b, j, a2r, a2i); a2i = -a2i;
      double zr = a1r*a2r - a1i*a2i, zi = a1r*a2i + a1i*a2r;
      for (int k = 0; k < d3; k++) {
        double cc = CCs[p][(i*d2 + j)*d3 + k];
        if (cc == 0.0) continue;
        double a3r, a3i;
        c2r_elem(l3, c, k, a3r, a3i);
        tr += (zr*a3r - zi*a3i) * cc;
        ti += (zr*a3i + zi*a3r) * cc;
      }
    }
    trs[idx] = tr; tis[idx] = ti;
  }
  __syncthreads();

  if (tid < 11) {
    int p = tid;
    int l1 = CG_L1[p], l2 = CG_L2[p], l3 = CG_L3[p];
    int d1 = 2*l1+1, d2 = 2*l2+1, d3 = 2*l3+1;
    double sr = 0.0, si = 0.0;
    for (int a = 0; a < d1; a++) for (int b = 0; b < d2; b++) for (int c = 0; c < d3; c++) {
      int idx = p*125 + a*25 + b*5 + c;
      sr += fabs(trs[idx]); si += fabs(tis[idx]);
    }
    int useR = (sr >= si);
    double nrm = 0.0;
    for (int a = 0; a < d1; a++) for (int b = 0; b < d2; b++) for (int c = 0; c < d3; c++) {
      int idx = p*125 + a*25 + b*5 + c;
      double v = useR ? trs[idx] : tis[idx];
      nrm += v * v;
    }
    scaleL[p] = sqrt((double)(2*l3+1)) / sqrt(nrm);
    useRL[p] = useR;
  }
  __syncthreads();

  for (int idx = tid; idx < 11*125; idx += 512) {
    int p = idx / 125, r = idx % 125;
    int a = r / 25, b = (r / 5) % 5, c = r % 5;
    int l1 = CG_L1[p], l2 = CG_L2[p], l3 = CG_L3[p];
    int d1 = 2*l1+1, d2 = 2*l2+1, d3 = 2*l3+1;
    if (a >= d1 || b >= d2 || c >= d3) continue;
    double v = useRL[p] ? trs[idx] : tis[idx];
    cg[CG_OFF[p] + (a*d2 + b)*d3 + c] = (float)(v * scaleL[p]);
  }
}

// ================= CSR build =================
__global__ void k_hist(const int* __restrict__ recv, int* __restrict__ counts) {
  int e = blockIdx.x * 256 + threadIdx.x;
  if (e < NEDGES) atomicAdd(&counts[recv[e]], 1);
}

__launch_bounds__(256)
__global__ void k_scan(const int* __restrict__ counts, int* __restrict__ off, int* __restrict__ cursor) {
  __shared__ int part[256];
  __shared__ int base[257];
  int t = threadIdx.x;
  const int CH = (NNODES + 255) / 256;
  int s = 0;
  for (int i = 0; i < CH; i++) { int n = t*CH + i; if (n < NNODES) s += counts[n]; }
  part[t] = s;
  __syncthreads();
  if (t == 0) { int acc = 0; for (int i = 0; i < 256; i++) { base[i] = acc; acc += part[i]; } base[256] = acc; }
  __syncthreads();
  int run = base[t];
  for (int i = 0; i < CH; i++) {
    int n = t*CH + i;
    if (n < NNODES) { int cn = counts[n]; off[n] = run; cursor[n] = run; run += cn; }
  }
  if (t == 255) off[NNODES] = base[256];
}

__global__ void k_bucket(const int* __restrict__ recv, int* __restrict__ cursor, int* __restrict__ eidx) {
  int e = blockIdx.x * 256 + threadIdx.x;
  if (e < NEDGES) { int p = atomicAdd(&cursor[recv[e]], 1); eidx[p] = e; }
}

// ================= MFMA weight pre-pack: MLP (once per interaction block) =================
template<int B>
__global__ void k_wprep(const float* __restrict__ w1, const float* __restrict__ w2,
                        const float* __restrict__ wo, __hip_bfloat16* __restrict__ wpk) {
  constexpr int NP = B ? 7 : 3;
  constexpr int NWO = 2 * NP*4 * 64 * 8;
  int idx = blockIdx.x * 256 + threadIdx.x;
  const float* w; int Nout, NOC, local, base;
  if (idx < 4096)            { w = w1; Nout = 64;    NOC = 4;    local = idx;        base = 0; }
  else if (idx < 8192)       { w = w2; Nout = 64;    NOC = 4;    local = idx - 4096; base = 4096; }
  else if (idx < 8192 + NWO) { w = wo; Nout = NP*64; NOC = NP*4; local = idx - 8192; base = 8192; }
  else return;
  int i = local & 7, lane = (local >> 3) & 63, rest = local >> 9;
  int oc = rest % NOC, ks = rest / NOC;
  int k = ks*32 + ((lane >> 4) * 8) + i;
  int col = oc*16 + (lane & 15);
  wpk[base + local] = __float2bfloat16(w[k*Nout + col]);
}

// ================= MFMA weight pre-pack: lin (once per interaction block) =================
template<int B>
__global__ void k_linprep(const float* __restrict__ lin0, const float* __restrict__ lin1,
                          const float* __restrict__ lin2, __hip_bfloat16* __restrict__ wlpk) {
  constexpr int KS0 = (B?2:1)*2, KS1 = (B?3:1)*2, KS2 = (B?2:1)*2;
  constexpr int N0 = KS0*2048, N1 = KS1*2048, N2 = KS2*2048;
  int idx = blockIdx.x * 256 + threadIdx.x;
  const float* w; int local, base;
  if (idx < N0)           { w = lin0; local = idx;          base = 0; }
  else if (idx < N0+N1)   { w = lin1; local = idx - N0;     base = N0; }
  else if (idx < N0+N1+N2){ w = lin2; local = idx - N0-N1;  base = N0+N1; }
  else return;
  int i = local & 7, lane = (local >> 3) & 63, rest = local >> 9;
  int oc = rest & 3, ks = rest >> 2;
  int k = ks*32 + ((lane >> 4) * 8) + i;
  int col = oc*16 + (lane & 15);
  wlpk[base + local] = __float2bfloat16(w[k*64 + col]);
}

// ================= helpers =================
template<int D1, int D2, int D3, int BASE, int ROWS>
__device__ __forceinline__ void tp_acc(const float (&yv)[D1], const float* shv, float wsc,
                                       const float* cgs, int offc, float (&acc)[ROWS]) {
  float m[D3];
#pragma unroll
  for (int mm = 0; mm < D3; mm++) m[mm] = 0.f;
#pragma unroll
  for (int i = 0; i < D1; i++)
#pragma unroll
    for (int j = 0; j < D2; j++) {
      float t = yv[i] * shv[j];
#pragma unroll
      for (int mm = 0; mm < D3; mm++) m[mm] += t * cgs[offc + (i*D2 + j)*D3 + mm];
    }
  float s = wsc * (1.f / 16.f);  // / AVG_NN
#pragma unroll
  for (int mm = 0; mm < D3; mm++) acc[BASE + mm] += s * m[mm];
}

template<int ROWS>
__device__ __forceinline__ void flush_acc(float (&acc)[ROWS], float* __restrict__ Agg,
                                          int rn, int lane) {
  float* aggn = Agg + (size_t)rn * (ROWS*64);
#pragma unroll
  for (int r = 0; r < ROWS; r++) {
    unsafeAtomicAdd(&aggn[r*64 + lane], acc[r]);
    acc[r] = 0.f;
  }
}

template<int D1, int D2, int D3>
__device__ __forceinline__ void pb_path(float cp, const float (&T)[D1], const float (&A)[D2],
                                        float (&NN)[D3], const float* cgs, int offc) {
#pragma unroll
  for (int i = 0; i < D1; i++)
#pragma unroll
    for (int j = 0; j < D2; j++) {
      float t = cp * T[i] * A[j];
#pragma unroll
      for (int mm = 0; mm < D3; mm++) NN[mm] += t * cgs[offc + (i*D2 + j)*D3 + mm];
    }
}

// ================= node pre: y = up(x), sc = elem-skip(x) =================
template<int B>
__launch_bounds__(256)
__global__ void k_node_pre(const float* __restrict__ x0, const float* __restrict__ x1,
                           const int* __restrict__ elem,
                           const float* __restrict__ upl0, const float* __restrict__ upl1,
                           const float* __restrict__ scw0, const float* __restrict__ scw1,
                           float* __restrict__ y0, float* __restrict__ y1,
                           float* __restrict__ sc0, float* __restrict__ sc1) {
  __shared__ float xs[4][4][64];
  int wid = threadIdx.x >> 6, lane = threadIdx.x & 63;
  int n = blockIdx.x * 4 + wid;
  xs[wid][0][lane] = x0[n*64 + lane];
  if (B) {
#pragma unroll
    for (int i = 0; i < 3; i++) xs[wid][1 + i][lane] = x1[(n*3 + i)*64 + lane];
  }
  __syncthreads();
  int z = elem[n];
  float a0 = 0.f, s0 = 0.f;
  float a1[3] = {0.f,0.f,0.f}, s1[3] = {0.f,0.f,0.f};
  for (int k = 0; k < 64; k++) {
    float xv = xs[wid][0][k];
    a0 += xv * upl0[k*64 + lane];
    s0 += xv * scw0[(z*64 + k)*64 + lane];
    if (B) {
      float uv = upl1[k*64 + lane];
      float sv = scw1[(z*64 + k)*64 + lane];
#pragma unroll
      for (int i = 0; i < 3; i++) {
        float xv1 = xs[wid][1 + i][k];
        a1[i] += xv1 * uv;
        s1[i] += xv1 * sv;
      }
    }
  }
  y0[n*64 + lane] = a0;
  sc0[n*64 + lane] = s0;
  if (B) {
#pragma unroll
    for (int i = 0; i < 3; i++) {
      y1[(n*3 + i)*64 + lane] = a1[i];
      sc1[(n*3 + i)*64 + lane] = s1[i];
    }
  }
}

// ================= k_mlp: radial MLP via MFMA, 16 edges/wave =================
template<int B>
__launch_bounds__(256)
__global__ void k_mlp(const float* __restrict__ er, const int* __restrict__ eidx,
                      const float* __restrict__ w0, const __hip_bfloat16* __restrict__ wpk,
                      __hip_bfloat16* __restrict__ wbuf, int ebase) {
  constexpr int NP = B ? 7 : 3;
  constexpr int NOC = NP * 4;
  __shared__ __align__(16) __hip_bfloat16 hsb[4][2][16][72];
  int wid = threadIdx.x >> 6, lane = threadIdx.x & 63;
  int g = blockIdx.x * 4 + wid;          // 16-edge group
  int base = ebase + g * 16;
  int col16 = lane & 15, kg = lane >> 4;

  int ev = (lane < 16) ? eidx[base + lane] : 0;

  // ---- layer 1: R=8 -> 64 (VALU, fp32 weights) ----
#pragma unroll 1
  for (int j = 0; j < 16; j++) {
    int e = __builtin_amdgcn_readlane(ev, j);
    float a = 0.f;
#pragma unroll
    for (int r = 0; r < 8; r++) a += er[e*8 + r] * w0[r*64 + lane];
    hsb[wid][0][j][lane] = __float2bfloat16(silu_f(a));
  }

  // ---- layers 2,3: 64->64 MFMA (src L, dst 1-L; wpk base L*4096) ----
#pragma unroll
  for (int L = 0; L < 2; L++) {
    const __hip_bfloat16* wp = wpk + L * 4096;
    bf16x8 A0 = *(const bf16x8*)&hsb[wid][L][col16][kg*8];
    bf16x8 A1 = *(const bf16x8*)&hsb[wid][L][col16][32 + kg*8];
    f32x4 acc[4];
#pragma unroll
    for (int oc = 0; oc < 4; oc++) acc[oc] = (f32x4){0.f,0.f,0.f,0.f};
#pragma unroll
    for (int ks = 0; ks < 2; ks++) {
      bf16x8 A = ks ? A1 : A0;
#pragma unroll
      for (int oc = 0; oc < 4; oc++) {
        bf16x8 Bf = *(const bf16x8*)&wp[((ks*4 + oc)*64 + lane)*8];
        acc[oc] = __builtin_amdgcn_mfma_f32_16x16x32_bf16(A, Bf, acc[oc], 0, 0, 0);
      }
    }
#pragma unroll
    for (int oc = 0; oc < 4; oc++)
#pragma unroll
      for (int i = 0; i < 4; i++)
        hsb[wid][1 - L][kg*4 + i][oc*16 + col16] = __float2bfloat16(silu_f(acc[oc][i]));
  }

  // ---- output layer: 64 -> NP*64 MFMA, serial col-tiles, stream to wbuf ----
  {
    bf16x8 A0 = *(const bf16x8*)&hsb[wid][0][col16][kg*8];
    bf16x8 A1 = *(const bf16x8*)&hsb[wid][0][col16][32 + kg*8];
    const __hip_bfloat16* wp = wpk + 8192;
#pragma unroll 1
    for (int oc = 0; oc < NOC; oc++) {
      f32x4 acc = (f32x4){0.f,0.f,0.f,0.f};
      bf16x8 B0 = *(const bf16x8*)&wp[((0*NOC + oc)*64 + lane)*8];
      bf16x8 B1 = *(const bf16x8*)&wp[((1*NOC + oc)*64 + lane)*8];
      acc = __builtin_amdgcn_mfma_f32_16x16x32_bf16(A0, B0, acc, 0, 0, 0);
      acc = __builtin_amdgcn_mfma_f32_16x16x32_bf16(A1, B1, acc, 0, 0, 0);
      int p = oc >> 2, chan = (oc & 3)*16 + col16;
#pragma unroll
      for (int i = 0; i < 4; i++) {
        int edge = kg*4 + i;
        wbuf[((size_t)(g*16 + edge) * NP + p)*64 + chan] = __float2bfloat16(acc[i]);
      }
    }
  }
}

// ================= k_tp: TP + receiver-run register-combine scatter =================
template<int B>
__launch_bounds__(256)
__global__ void k_tp(const float* __restrict__ esh,
                     const int* __restrict__ senders, const int* __restrict__ receivers,
                     const int* __restrict__ eidx,
                     const float* __restrict__ y0, const float* __restrict__ y1,
                     const __hip_bfloat16* __restrict__ wbuf, const float* __restrict__ cg,
                     float* __restrict__ Agg, int ebase) {
  constexpr int NP = B ? 7 : 3;
  constexpr int ROWS = B ? 21 : 9;
  constexpr int EPW = 32;
  __shared__ float cgs[363];
  int wid = threadIdx.x >> 6, lane = threadIdx.x & 63;
  for (int i = threadIdx.x; i < 363; i += 256) cgs[i] = cg[i];
  __syncthreads();

  int g = blockIdx.x * 4 + wid;
  int base = ebase + g * EPW;

  int ev = 0, rv = 0, sv = 0;
  if (lane < EPW) ev = eidx[base + lane];
  if (lane < EPW) { rv = receivers[ev]; sv = senders[ev]; }

  float acc[ROWS];
#pragma unroll
  for (int r = 0; r < ROWS; r++) acc[r] = 0.f;
  int rprev = -1;
#pragma unroll 1
  for (int j = 0; j < EPW; j++) {
    int e  = __builtin_amdgcn_readlane(ev, j);
    int r  = __builtin_amdgcn_readlane(rv, j);
    int sn = __builtin_amdgcn_readlane(sv, j);
    if (j > 0 && r != rprev) flush_acc<ROWS>(acc, Agg, rprev, lane);
    rprev = r;
    const __hip_bfloat16* wj = wbuf + ((size_t)(g*EPW + j)) * NP * 64 + lane;
    float w[NP];
#pragma unroll
    for (int p = 0; p < NP; p++) w[p] = __bfloat162float(wj[p*64]);
    float y0a[1] = { y0[sn*64 + lane] };
    float sh[9];
#pragma unroll
    for (int q = 0; q < 9; q++) sh[q] = esh[e*9 + q];
    if constexpr (B == 0) {
      tp_acc<1,1,1,0>(y0a, sh + 0, w[0], cgs, 0,  acc);
      tp_acc<1,3,3,1>(y0a, sh + 1, w[1], cgs, 1,  acc);
      tp_acc<1,5,5,4>(y0a, sh + 4, w[2], cgs, 10, acc);
    } else {
      tp_acc<1,1,1,0> (y0a, sh + 0, w[0], cgs, 0,  acc);
      tp_acc<1,3,3,2> (y0a, sh + 1, w[1], cgs, 1,  acc);
      tp_acc<1,5,5,11>(y0a, sh + 4, w[2], cgs, 10, acc);
      float y1a[3];
#pragma unroll
      for (int i = 0; i < 3; i++) y1a[i] = y1[(sn*3 + i)*64 + lane];
      tp_acc<3,1,3,5> (y1a, sh + 0, w[3], cgs, 35, acc);
      tp_acc<3,3,1,1> (y1a, sh + 1, w[4], cgs, 44, acc);
      tp_acc<3,3,5,16>(y1a, sh + 1, w[5], cgs, 53, acc);
      tp_acc<3,5,3,8> (y1a, sh + 4, w[6], cgs, 98, acc);
    }
  }
  flush_acc<ROWS>(acc, Agg, rprev, lane);
}

// ================= k_lin: A = lin(Agg) via MFMA, in place =================
template<int D, int KS>
__device__ __forceinline__ void lin_phase(const float* __restrict__ anA, int rowsx64_unused,
                                          const __hip_bfloat16* __restrict__ wp,
                                          int oc, int lane, int inbase, int stride64,
                                          f32x4 (&acc)[D]) {
#pragma unroll
  for (int i = 0; i < D; i++) {
    f32x4 a = (f32x4){0.f,0.f,0.f,0.f};
#pragma unroll
    for (int ks = 0; ks < KS; ks++) {
      int kglob = ks*32 + ((lane >> 4) * 8);
      int P = kglob >> 6, ch = kglob & 63;
      bf16x8 A = cvt8(anA + (inbase + P*stride64 + i)*64 + ch);
      bf16x8 Bf = *(const bf16x8*)&wp[((ks*4 + oc)*64 + lane)*8];
      a = __builtin_amdgcn_mfma_f32_16x16x32_bf16(A, Bf, a, 0, 0, 0);
    }
    acc[i] = a;
  }
}

template<int B>
__launch_bounds__(256)
__global__ void k_lin(float* __restrict__ Agg, const __hip_bfloat16* __restrict__ wlpk) {
  constexpr int P0 = B ? 2 : 1, P1 = B ? 3 : 1, P2 = B ? 2 : 1;
  constexpr int ROWS = P0 + 3*P1 + 5*P2;
  constexpr int BASE1 = P0, BASE2 = P0 + 3*P1;
  constexpr int KS0 = P0*2, KS1 = P1*2, KS2 = P2*2;
  constexpr int OFF1 = KS0*2048, OFF2 = OFF1 + KS1*2048;
  int wid = threadIdx.x >> 6, lane = threadIdx.x & 63;
  int oc = wid;
  int n0 = blockIdx.x * 16;
  int m = lane & 15;
  const float* anA = Agg + (size_t)(n0 + m) * (ROWS*64);

  f32x4 a0[1], a1[3], a2[5];
  lin_phase<1, KS0>(anA, 0, wlpk,        oc, lane, 0,     1, a0);
  lin_phase<3, KS1>(anA, 0, wlpk + OFF1, oc, lane, BASE1, 3, a1);
  lin_phase<5, KS2>(anA, 0, wlpk + OFF2, oc, lane, BASE2, 5, a2);

  __syncthreads();   // all reads in block done before any write

  int col = oc*16 + (lane & 15);
  int kg = lane >> 4;
#pragma unroll
  for (int r = 0; r < 4; r++) {
    float* an = Agg + (size_t)(n0 + kg*4 + r) * (ROWS*64);
    an[0*64 + col] = a0[0][r];
#pragma unroll
    for (int i = 0; i < 3; i++) an[(1 + i)*64 + col] = a1[i][r];
#pragma unroll
    for (int i = 0; i < 5; i++) an[(4 + i)*64 + col] = a2[i][r];
  }
}

// ================= node post, phase 2+3 fused: product basis + out GEMV =================
// LDS: only plin0/plin1 (32KB, the per-node-reuse win) + cgs. The z-indexed
// w2p/w3p/wnu tables (11/11/6 KB total) are L2-resident -> direct reads.
// it-loop NOT unrolled: full unroll kept two copies of the 11-path CG chain
// live -> 212 VGPR -> 2 waves/SIMD (round-19 counters).
template<int B>
__launch_bounds__(256)
__global__ void k_pbout(const float* __restrict__ Agg, const int* __restrict__ elem,
                        const float* __restrict__ w2p, const float* __restrict__ w3p,
                        const float* __restrict__ wnu, const float* __restrict__ cg,
                        const float* __restrict__ plin0, const float* __restrict__ plin1,
                        const float* __restrict__ sc0, const float* __restrict__ sc1,
                        float* __restrict__ x0n, float* __restrict__ x1n,
                        float* __restrict__ out, int obase, int npb) {
  constexpr int ROWS = B ? 21 : 9;
  __shared__ float cgs[363];
  __shared__ float p0s[64*64];
  __shared__ float p1s[64*64];
  __shared__ float Bs[4][4][64];
  int wid = threadIdx.x >> 6, lane = threadIdx.x & 63;
  for (int i = threadIdx.x; i < 363; i += 256) cgs[i] = cg[i];
  for (int i = threadIdx.x; i < 64*64; i += 256) { p0s[i] = plin0[i]; p1s[i] = plin1[i]; }
  __syncthreads();

  int n0 = blockIdx.x * npb;
  int nend = n0 + npb; if (nend > NNODES) nend = NNODES;
  for (int n = n0 + wid; n < nend; n += 4) {
    int z = elem[n];
    const float* an = Agg + (size_t)n * (ROWS*64);
    float A0[1] = { an[0*64 + lane] };
    float A1[3], A2[5];
#pragma unroll
    for (int i = 0; i < 3; i++) A1[i] = an[(1 + i)*64 + lane];
#pragma unroll
    for (int i = 0; i < 5; i++) A2[i] = an[(4 + i)*64 + lane];

    float T0[1] = {A0[0]};
    float T1[3], T2[5];
#pragma unroll
    for (int i = 0; i < 3; i++) T1[i] = A1[i];
#pragma unroll
    for (int i = 0; i < 5; i++) T2[i] = A2[i];
    float s10 = 0.f, s11[3] = {0.f,0.f,0.f}, s20 = 0.f, s21[3] = {0.f,0.f,0.f};
#pragma unroll 1
    for (int it = 0; it < 2; it++) {
      const float* wp = it ? w3p : w2p;
      float c[11];
#pragma unroll
      for (int p = 0; p < 11; p++) c[p] = wp[(z*11 + p)*64 + lane];
      float n0v[1] = {0.f}, n1v[3] = {0.f,0.f,0.f}, n2v[5] = {0.f,0.f,0.f,0.f,0.f};
      pb_path<1,1,1>(c[0],  T0, A0, n0v, cgs, 0);
      pb_path<1,3,3>(c[1],  T0, A1, n1v, cgs, 1);
      pb_path<1,5,5>(c[2],  T0, A2, n2v, cgs, 10);
      pb_path<3,1,3>(c[3],  T1, A0, n1v, cgs, 35);
      pb_path<3,3,1>(c[4],  T1, A1, n0v, cgs, 44);
      pb_path<3,3,5>(c[5],  T1, A1, n2v, cgs, 53);
      pb_path<3,5,3>(c[6],  T1, A2, n1v, cgs, 98);
      pb_path<5,1,5>(c[7],  T2, A0, n2v, cgs, 143);
      pb_path<5,3,3>(c[8],  T2, A1, n1v, cgs, 168);
      pb_path<5,5,1>(c[9],  T2, A2, n0v, cgs, 213);
      pb_path<5,5,5>(c[10], T2, A2, n2v, cgs, 238);
      T0[0] = n0v[0];
#pragma unroll
      for (int i = 0; i < 3; i++) T1[i] = n1v[i];
#pragma unroll
      for (int i = 0; i < 5; i++) T2[i] = n2v[i];
      if (it == 0) {
        s10 = n0v[0];
#pragma unroll
        for (int i = 0; i < 3; i++) s11[i] = n1v[i];
      } else {
        s20 = n0v[0];
#pragma unroll
        for (int i = 0; i < 3; i++) s21[i] = n1v[i];
      }
    }

    float c00 = wnu[((z*3 + 0)*2 + 0)*64 + lane];
    float c10 = wnu[((z*3 + 1)*2 + 0)*64 + lane];
    float c20 = wnu[((z*3 + 2)*2 + 0)*64 + lane];
    float c01 = wnu[((z*3 + 0)*2 + 1)*64 + lane];
    float c11 = wnu[((z*3 + 1)*2 + 1)*64 + lane];
    float c21 = wnu[((z*3 + 2)*2 + 1)*64 + lane];
    Bs[wid][0][lane] = c00*A0[0] + c10*s10 + c20*s20;
#pragma unroll
    for (int i = 0; i < 3; i++)
      Bs[wid][1 + i][lane] = c01*A1[i] + c11*s11[i] + c21*s21[i];
    // same wave consumes Bs (within-wave LDS RAW order) -> no barrier

    float x0v = 0.f, x1v[3] = {0.f,0.f,0.f};
    for (int k = 0; k < 64; k++) {
      float p0v = p0s[k*64 + lane];
      float p1v = p1s[k*64 + lane];
      x0v += Bs[wid][0][k] * p0v;
#pragma unroll
      for (int i = 0; i < 3; i++) x1v[i] += Bs[wid][1 + i][k] * p1v;
    }
    x0v += sc0[n*64 + lane];
    if (B) {
#pragma unroll
      for (int i = 0; i < 3; i++) x1v[i] += sc1[(n*3 + i)*64 + lane];
    }
    if (B == 0) {
      x0n[n*64 + lane] = x0v;
#pragma unroll
      for (int i = 0; i < 3; i++) x1n[(n*3 + i)*64 + lane] = x1v[i];
    }
    out[(size_t)n*512 + obase + lane] = x0v;
#pragma unroll
    for (int i = 0; i < 3; i++)
      out[(size_t)n*512 + obase + 64 + lane*3 + i] = x1v[i];
  }
}

// ================= launch =================
extern "C" void kernel_launch(void* const* d_in, const int* in_sizes, int n_in,
                              void* d_out, int out_size, void* d_ws, size_t ws_size,
                              hipStream_t stream) {
  const float* node_feats  = (const float*)d_in[0];
  const int*   node_elem   = (const int*)  d_in[1];
  const float* edge_sh     = (const float*)d_in[2];
  const float* edge_radial = (const float*)d_in[3];
  const int*   senders     = (const int*)  d_in[4];
  const int*   receivers   = (const int*)  d_in[5];
  const float* up0_l0   = (const float*)d_in[6];
  const float* r0_w0    = (const float*)d_in[7];
  const float* r0_w1    = (const float*)d_in[8];
  const float* r0_w2    = (const float*)d_in[9];
  const float* r0_wo    = (const float*)d_in[10];
  const float* lin0_l0  = (const float*)d_in[11];
  const float* lin0_l1  = (const float*)d_in[12];
  const float* lin0_l2  = (const float*)d_in[13];
  const float* sc0_l0   = (const float*)d_in[14];
  const float* p0_w2    = (const float*)d_in[15];
  const float* p0_w3    = (const float*)d_in[16];
  const float* p0_wnu   = (const float*)d_in[17];
  const float* p0_lin_l0= (const float*)d_in[18];
  const float* p0_lin_l1= (const float*)d_in[19];
  const float* up1_l0   = (const float*)d_in[20];
  const float* up1_l1   = (const float*)d_in[21];
  const float* r1_w0    = (const float*)d_in[22];
  const float* r1_w1    = (const float*)d_in[23];
  const float* r1_w2    = (const float*)d_in[24];
  const float* r1_wo    = (const float*)d_in[25];
  const float* lin1_l0  = (const float*)d_in[26];
  const float* lin1_l1  = (const float*)d_in[27];
  const float* lin1_l2  = (const float*)d_in[28];
  const float* sc1_l0   = (const float*)d_in[29];
  const float* sc1_l1   = (const float*)d_in[30];
  const float* p1_w2    = (const float*)d_in[31];
  const float* p1_w3    = (const float*)d_in[32];
  const float* p1_wnu   = (const float*)d_in[33];
  const float* p1_lin_l0= (const float*)d_in[34];
  const float* p1_lin_l1= (const float*)d_in[35];

  float* ws  = (float*)d_ws;
  float* cg  = ws + WS_CG;
  float* y0  = ws + WS_Y0;
  float* y1  = ws + WS_Y1;
  float* sc0 = ws + WS_SC0;
  float* sc1 = ws + WS_SC1;
  float* x0n = ws + WS_X0N;
  float* x1n = ws + WS_X1N;
  float* Agg = ws + WS_AGG;
  int* counts = (int*)(ws + WS_CSR);
  int* off    = counts + NNODES;       // NNODES+1
  int* cursor = off + NNODES + 1;      // NNODES
  int* eidx   = cursor + NNODES;       // NEDGES
  __hip_bfloat16* wpk  = (__hip_bfloat16*)(ws + WS_WPK);
  __hip_bfloat16* wlpk = (__hip_bfloat16*)(ws + WS_WLPK);
  __hip_bfloat16* wbuf = (__hip_bfloat16*)(ws + WS_WBUF);
  float* out = (float*)d_out;

  // chunk size from available workspace (bf16 rows of 7*64 elems, 128-edge aligned)
  size_t cap_bytes = (ws_size > (size_t)WS_WBUF*4) ? ws_size - (size_t)WS_WBUF*4 : 0;
  int chunk = 131072;
  if (cap_bytes < (size_t)chunk * 7 * 64 * 2) {
    chunk = (int)((cap_bytes / (7*64*2)) & ~(size_t)127);
    if (chunk < 128) chunk = 128;
  }
  const int NPB = 32;                       // nodes per k_pbout block
  const int NODE_BLOCKS = (NNODES + NPB - 1) / NPB;

  k_cg<<<1, 512, 0, stream>>>(cg);

  // ---- CSR/sort build (shared by both blocks) ----
  hipMemsetAsync(counts, 0, NNODES * sizeof(int), stream);
  k_hist<<<(NEDGES + 255) / 256, 256, 0, stream>>>(receivers, counts);
  k_scan<<<1, 256, 0, stream>>>(counts, off, cursor);
  k_bucket<<<(NEDGES + 255) / 256, 256, 0, stream>>>(receivers, cursor, eidx);

  // ---- interaction block 0 ----
  k_node_pre<0><<<NNODES/4, 256, 0, stream>>>(node_feats, nullptr, node_elem,
                                              up0_l0, nullptr, sc0_l0, nullptr,
                                              y0, y1, sc0, sc1);
  hipMemsetAsync(Agg, 0, (size_t)NNODES * 9 * 64 * sizeof(float), stream);
  k_wprep<0><<<(8192 + 2*3*4*512 + 255)/256, 256, 0, stream>>>(r0_w1, r0_w2, r0_wo, wpk);
  k_linprep<0><<<(6*2048 + 255)/256, 256, 0, stream>>>(lin0_l0, lin0_l1, lin0_l2, wlpk);
  for (int e0 = 0; e0 < NEDGES; e0 += chunk) {
    int ce = (NEDGES - e0 < chunk) ? (NEDGES - e0) : chunk;
    k_mlp<0><<<ce/64, 256, 0, stream>>>(edge_radial, eidx, r0_w0, wpk, wbuf, e0);
    k_tp<0><<<ce/128, 256, 0, stream>>>(edge_sh, senders, receivers, eidx, y0, y1, wbuf, cg, Agg, e0);
  }
  k_lin<0><<<NNODES/16, 256, 0, stream>>>(Agg, wlpk);
  k_pbout<0><<<NODE_BLOCKS, 256, 0, stream>>>(Agg, node_elem, p0_w2, p0_w3, p0_wnu, cg,
                                              p0_lin_l0, p0_lin_l1, sc0, sc1,
                                              x0n, x1n, out, 0, NPB);

  // ---- interaction block 1 ----
  k_node_pre<1><<<NNODES/4, 256, 0, stream>>>(x0n, x1n, node_elem,
                                              up1_l0, up1_l1, sc1_l0, sc1_l1,
                                              y0, y1, sc0, sc1);
  hipMemsetAsync(Agg, 0, (size_t)NNODES * 21 * 64 * sizeof(float), stream);
  k_wprep<1><<<(8192 + 2*7*4*512 + 255)/256, 256, 0, stream>>>(r1_w1, r1_w2, r1_wo, wpk);
  k_linprep<1><<<(14*2048 + 255)/256, 256, 0, stream>>>(lin1_l0, lin1_l1, lin1_l2, wlpk);
  for (int e0 = 0; e0 < NEDGES; e0 += chunk) {
    int ce = (NEDGES - e0 < chunk) ? (NEDGES - e0) : chunk;
    k_mlp<1><<<ce/64, 256, 0, stream>>>(edge_radial, eidx, r1_w0, wpk, wbuf, e0);
    k_tp<1><<<ce/128, 256, 0, stream>>>(edge_sh, senders, receivers, eidx, y0, y1, wbuf, cg, Agg, e0);
  }
  k_lin<1><<<NNODES/16, 256, 0, stream>>>(Agg, wlpk);
  k_pbout<1><<<NODE_BLOCKS, 256, 0, stream>>>(Agg, node_elem, p1_w2, p1_w3, p1_wnu, cg,
                                              p1_lin_l0, p1_lin_l1, sc0, sc1,
                                              x0n, x1n, out, 256, NPB);
}

// Round 21
// 816.859 us; speedup vs baseline: 1.2887x; 1.2887x over previous
//
#include <hip/hip_runtime.h>
#include <hip/hip_bf16.h>
#include <math.h>

#define NNODES 16000
#define NEDGES 256000

typedef float v2f __attribute__((ext_vector_type(2)));
typedef short bf16x8 __attribute__((ext_vector_type(8)));
typedef float f32x4 __attribute__((ext_vector_type(4)));

// ---------------- ws layout (float element offsets) ----------------
#define WS_CG   0
#define WS_Y0   512
#define WS_Y1   (WS_Y0 + NNODES*64)
#define WS_SC0  (WS_Y1 + NNODES*192)
#define WS_SC1  (WS_SC0 + NNODES*64)
#define WS_BIG  (WS_SC1 + NNODES*192)
#define WS_AGG  WS_BIG
#define WS_X0N  (WS_BIG + NNODES*9*64)
#define WS_X1N  (WS_X0N + NNODES*64)
#define WS_CSR  (WS_BIG + NNODES*21*64)   // int region: counts|off|cursor|eidx
#define WS_WPK  (WS_CSR + 310000)         // MFMA-packed MLP weights (bf16, 36864)
#define WS_WLPK (WS_WPK + 18432)          // MFMA-packed lin weights (bf16, <=28672)
#define WS_WBUF (WS_WLPK + 14336)         // per-edge TP-weight buffer (bf16, chunked)
// A is written IN PLACE over Agg rows 0..8 per node (k_lin).

// CG dense storage offsets for PATHS_P (l1,l2,l3):
// p0 (0,0,0) off 0   | p1 (0,1,1) off 1  | p2 (0,2,2) off 10 | p3 (1,0,1) off 35
// p4 (1,1,0) off 44  | p5 (1,1,2) off 53 | p6 (1,2,1) off 98 | p7 (2,0,2) off 143
// p8 (2,1,1) off 168 | p9 (2,2,0) off 213| p10(2,2,2) off 238  -> total 363

__device__ __forceinline__ float silu_f(float x) { return x / (1.f + expf(-x)); }
__device__ __forceinline__ short f2bs(float x) {
  __hip_bfloat16 h = __float2bfloat16(x);
  return *reinterpret_cast<short*>(&h);
}
__device__ __forceinline__ bf16x8 cvt8(const float* p) {
  float4 a = *(const float4*)p, b = *(const float4*)(p + 4);
  bf16x8 r;
  r[0]=f2bs(a.x); r[1]=f2bs(a.y); r[2]=f2bs(a.z); r[3]=f2bs(a.w);
  r[4]=f2bs(b.x); r[5]=f2bs(b.y); r[6]=f2bs(b.z); r[7]=f2bs(b.w);
  return r;
}

// ================= CG init: LDS-parallel, one 512-thread block =================
__device__ __forceinline__ void c2r_elem(int l, int r, int c, double& re, double& im) {
  re = 0.0; im = 0.0;
  int mr = r - l, mc = c - l;
  const double s = 0.70710678118654752440;
  if (mr == 0) { if (mc == 0) re = 1.0; return; }
  if (mr > 0) {
    double sg = (mr & 1) ? -1.0 : 1.0;
    if (mc == mr) re = sg * s;
    else if (mc == -mr) re = s;
  } else {
    int m = -mr;
    double sg = (m & 1) ? -1.0 : 1.0;
    if (mc == m) im = -sg * s;
    else if (mc == -m) im = s;
  }
}

__constant__ int CG_L1[11] = {0,0,0,1,1,1,1,2,2,2,2};
__constant__ int CG_L2[11] = {0,1,2,0,1,1,2,0,1,2,2};
__constant__ int CG_L3[11] = {0,1,2,1,0,2,1,2,1,0,2};
__constant__ int CG_OFF[11] = {0,1,10,35,44,53,98,143,168,213,238};
__constant__ double CG_FACT[8] = {1.,1.,2.,6.,24.,120.,720.,5040.};

__launch_bounds__(512)
__global__ void k_cg(float* __restrict__ cg) {
  __shared__ double CCs[11][125];
  __shared__ double trs[11*125];
  __shared__ double tis[11*125];
  __shared__ double scaleL[11];
  __shared__ int useRL[11];
  int tid = threadIdx.x;

  for (int i = tid; i < 11*125; i += 512) CCs[i/125][i%125] = 0.0;
  __syncthreads();

  for (int idx = tid; idx < 11*25; idx += 512) {
    int p = idx / 25, r = idx % 25;
    int i1 = r / 5, i2 = r % 5;
    int l1 = CG_L1[p], l2 = CG_L2[p], l3 = CG_L3[p];
    int d2 = 2*l2+1, d3 = 2*l3+1;
    if (i1 >= 2*l1+1 || i2 >= d2) continue;
    int m1 = i1 - l1, m2 = i2 - l2, m3 = m1 + m2;
    if (m3 < -l3 || m3 > l3) continue;
    double pre0 = sqrt((double)(2*l3+1) * CG_FACT[l3+l1-l2] * CG_FACT[l3-l1+l2]
                       * CG_FACT[l1+l2-l3] / CG_FACT[l1+l2+l3+1]);
    double pre = pre0 * sqrt(CG_FACT[l3+m3]*CG_FACT[l3-m3]*CG_FACT[l1-m1]
                             *CG_FACT[l1+m1]*CG_FACT[l2-m2]*CG_FACT[l2+m2]);
    double ssum = 0.0;
    for (int k = 0; k <= l1 + l2 - l3; k++) {
      int a2 = l1-m1-k, a3 = l2+m2-k, a4 = l3-l2+m1+k, a5 = l3-l1-m2+k;
      if (a2 < 0 || a3 < 0 || a4 < 0 || a5 < 0) continue;
      double den = CG_FACT[k]*CG_FACT[l1+l2-l3-k]*CG_FACT[a2]*CG_FACT[a3]*CG_FACT[a4]*CG_FACT[a5];
      ssum += ((k & 1) ? -1.0 : 1.0) / den;
    }
    CCs[p][(i1*d2 + i2)*d3 + (m3 + l3)] = pre * ssum;
  }
  __syncthreads();

  for (int idx = tid; idx < 11*125; idx += 512) {
    int p = idx / 125, r = idx % 125;
    int a = r / 25, b = (r / 5) % 5, c = r % 5;
    int l1 = CG_L1[p], l2 = CG_L2[p], l3 = CG_L3[p];
    int d1 = 2*l1+1, d2 = 2*l2+1, d3 = 2*l3+1;
    if (a >= d1 || b >= d2 || c >= d3) continue;
    double tr = 0.0, ti = 0.0;
    for (int i = 0; i < d1; i++) for (int j = 0; j < d2; j++) {
      double a1r, a1i, a2r, a2i;
      c2r_elem(l1, a, i, a1r, a1i); a1i = -a1i;
      c2r_elem(l2, b, j, a2r, a2i); a2i = -a2i;
      double zr = a1r*a2r - a1i*a2i, zi = a1r*a2i + a1i*a2r;
      for (int k = 0; k < d3; k++) {
        double cc = CCs[p][(i*d2 + j)*d3 + k];
        if (cc == 0.0) continue;
        double a3r, a3i;
        c2r_elem(l3, c, k, a3r, a3i);
        tr += (zr*a3r - zi*a3i) * cc;
        ti += (zr*a3i + zi*a3r) * cc;
      }
    }
    trs[idx] = tr; tis[idx] = ti;
  }
  __syncthreads();

  if (tid < 11) {
    int p = tid;
    int l1 = CG_L1[p], l2 = CG_L2[p], l3 = CG_L3[p];
    int d1 = 2*l1+1, d2 = 2*l2+1, d3 = 2*l3+1;
    double sr = 0.0, si = 0.0;
    for (int a = 0; a < d1; a++) for (int b = 0; b < d2; b++) for (int c = 0; c < d3; c++) {
      int idx = p*125 + a*25 + b*5 + c;
      sr += fabs(trs[idx]); si += fabs(tis[idx]);
    }
    int useR = (sr >= si);
    double nrm = 0.0;
    for (int a = 0; a < d1; a++) for (int b = 0; b < d2; b++) for (int c = 0; c < d3; c++) {
      int idx = p*125 + a*25 + b*5 + c;
      double v = useR ? trs[idx] : tis[idx];
      nrm += v * v;
    }
    scaleL[p] = sqrt((double)(2*l3+1)) / sqrt(nrm);
    useRL[p] = useR;
  }
  __syncthreads();

  for (int idx = tid; idx < 11*125; idx += 512) {
    int p = idx / 125, r = idx % 125;
    int a = r / 25, b = (r / 5) % 5, c = r % 5;
    int l1 = CG_L1[p], l2 = CG_L2[p], l3 = CG_L3[p];
    int d1 = 2*l1+1, d2 = 2*l2+1, d3 = 2*l3+1;
    if (a >= d1 || b >= d2 || c >= d3) continue;
    double v = useRL[p] ? trs[idx] : tis[idx];
    cg[CG_OFF[p] + (a*d2 + b)*d3 + c] = (float)(v * scaleL[p]);
  }
}

// ================= CSR build =================
__global__ void k_hist(const int* __restrict__ recv, int* __restrict__ counts) {
  int e = blockIdx.x * 256 + threadIdx.x;
  if (e < NEDGES) atomicAdd(&counts[recv[e]], 1);
}

__launch_bounds__(256)
__global__ void k_scan(const int* __restrict__ counts, int* __restrict__ off, int* __restrict__ cursor) {
  __shared__ int part[256];
  __shared__ int base[257];
  int t = threadIdx.x;
  const int CH = (NNODES + 255) / 256;
  int s = 0;
  for (int i = 0; i < CH; i++) { int n = t*CH + i; if (n < NNODES) s += counts[n]; }
  part[t] = s;
  __syncthreads();
  if (t == 0) { int acc = 0; for (int i = 0; i < 256; i++) { base[i] = acc; acc += part[i]; } base[256] = acc; }
  __syncthreads();
  int run = base[t];
  for (int i = 0; i < CH; i++) {
    int n = t*CH + i;
    if (n < NNODES) { int cn = counts[n]; off[n] = run; cursor[n] = run; run += cn; }
  }
  if (t == 255) off[NNODES] = base[256];
}

__global__ void k_bucket(const int* __restrict__ recv, int* __restrict__ cursor, int* __restrict__ eidx) {
  int e = blockIdx.x * 256 + threadIdx.x;
  if (e < NEDGES) { int p = atomicAdd(&cursor[recv[e]], 1); eidx[p] = e; }
}

// ================= MFMA weight pre-pack: MLP (once per interaction block) =================
template<int B>
__global__ void k_wprep(const float* __restrict__ w1, const float* __restrict__ w2,
                        const float* __restrict__ wo, __hip_bfloat16* __restrict__ wpk) {
  constexpr int NP = B ? 7 : 3;
  constexpr int NWO = 2 * NP*4 * 64 * 8;
  int idx = blockIdx.x * 256 + threadIdx.x;
  const float* w; int Nout, NOC, local, base;
  if (idx < 4096)            { w = w1; Nout = 64;    NOC = 4;    local = idx;        base = 0; }
  else if (idx < 8192)       { w = w2; Nout = 64;    NOC = 4;    local = idx - 4096; base = 4096; }
  else if (idx < 8192 + NWO) { w = wo; Nout = NP*64; NOC = NP*4; local = idx - 8192; base = 8192; }
  else return;
  int i = local & 7, lane = (local >> 3) & 63, rest = local >> 9;
  int oc = rest % NOC, ks = rest / NOC;
  int k = ks*32 + ((lane >> 4) * 8) + i;
  int col = oc*16 + (lane & 15);
  wpk[base + local] = __float2bfloat16(w[k*Nout + col]);
}

// ================= MFMA weight pre-pack: lin (once per interaction block) =================
template<int B>
__global__ void k_linprep(const float* __restrict__ lin0, const float* __restrict__ lin1,
                          const float* __restrict__ lin2, __hip_bfloat16* __restrict__ wlpk) {
  constexpr int KS0 = (B?2:1)*2, KS1 = (B?3:1)*2, KS2 = (B?2:1)*2;
  constexpr int N0 = KS0*2048, N1 = KS1*2048, N2 = KS2*2048;
  int idx = blockIdx.x * 256 + threadIdx.x;
  const float* w; int local, base;
  if (idx < N0)           { w = lin0; local = idx;          base = 0; }
  else if (idx < N0+N1)   { w = lin1; local = idx - N0;     base = N0; }
  else if (idx < N0+N1+N2){ w = lin2; local = idx - N0-N1;  base = N0+N1; }
  else return;
  int i = local & 7, lane = (local >> 3) & 63, rest = local >> 9;
  int oc = rest & 3, ks = rest >> 2;
  int k = ks*32 + ((lane >> 4) * 8) + i;
  int col = oc*16 + (lane & 15);
  wlpk[base + local] = __float2bfloat16(w[k*64 + col]);
}

// ================= helpers =================
template<int D1, int D2, int D3, int BASE, int ROWS>
__device__ __forceinline__ void tp_acc(const float (&yv)[D1], const float* shv, float wsc,
                                       const float* cgs, int offc, float (&acc)[ROWS]) {
  float m[D3];
#pragma unroll
  for (int mm = 0; mm < D3; mm++) m[mm] = 0.f;
#pragma unroll
  for (int i = 0; i < D1; i++)
#pragma unroll
    for (int j = 0; j < D2; j++) {
      float t = yv[i] * shv[j];
#pragma unroll
      for (int mm = 0; mm < D3; mm++) m[mm] += t * cgs[offc + (i*D2 + j)*D3 + mm];
    }
  float s = wsc * (1.f / 16.f);  // / AVG_NN
#pragma unroll
  for (int mm = 0; mm < D3; mm++) acc[BASE + mm] += s * m[mm];
}

template<int ROWS>
__device__ __forceinline__ void flush_acc(float (&acc)[ROWS], float* __restrict__ Agg,
                                          int rn, int lane) {
  float* aggn = Agg + (size_t)rn * (ROWS*64);
#pragma unroll
  for (int r = 0; r < ROWS; r++) {
    unsafeAtomicAdd(&aggn[r*64 + lane], acc[r]);
    acc[r] = 0.f;
  }
}

template<int D1, int D2, int D3>
__device__ __forceinline__ void pb_path(float cp, const float (&T)[D1], const float (&A)[D2],
                                        float (&NN)[D3], const float* cgs, int offc) {
#pragma unroll
  for (int i = 0; i < D1; i++)
#pragma unroll
    for (int j = 0; j < D2; j++) {
      float t = cp * T[i] * A[j];
#pragma unroll
      for (int mm = 0; mm < D3; mm++) NN[mm] += t * cgs[offc + (i*D2 + j)*D3 + mm];
    }
}

// ================= node pre: y = up(x), sc = elem-skip(x) =================
template<int B>
__launch_bounds__(256)
__global__ void k_node_pre(const float* __restrict__ x0, const float* __restrict__ x1,
                           const int* __restrict__ elem,
                           const float* __restrict__ upl0, const float* __restrict__ upl1,
                           const float* __restrict__ scw0, const float* __restrict__ scw1,
                           float* __restrict__ y0, float* __restrict__ y1,
                           float* __restrict__ sc0, float* __restrict__ sc1) {
  __shared__ float xs[4][4][64];
  int wid = threadIdx.x >> 6, lane = threadIdx.x & 63;
  int n = blockIdx.x * 4 + wid;
  xs[wid][0][lane] = x0[n*64 + lane];
  if (B) {
#pragma unroll
    for (int i = 0; i < 3; i++) xs[wid][1 + i][lane] = x1[(n*3 + i)*64 + lane];
  }
  __syncthreads();
  int z = elem[n];
  float a0 = 0.f, s0 = 0.f;
  float a1[3] = {0.f,0.f,0.f}, s1[3] = {0.f,0.f,0.f};
  for (int k = 0; k < 64; k++) {
    float xv = xs[wid][0][k];
    a0 += xv * upl0[k*64 + lane];
    s0 += xv * scw0[(z*64 + k)*64 + lane];
    if (B) {
      float uv = upl1[k*64 + lane];
      float sv = scw1[(z*64 + k)*64 + lane];
#pragma unroll
      for (int i = 0; i < 3; i++) {
        float xv1 = xs[wid][1 + i][k];
        a1[i] += xv1 * uv;
        s1[i] += xv1 * sv;
      }
    }
  }
  y0[n*64 + lane] = a0;
  sc0[n*64 + lane] = s0;
  if (B) {
#pragma unroll
    for (int i = 0; i < 3; i++) {
      y1[(n*3 + i)*64 + lane] = a1[i];
      sc1[(n*3 + i)*64 + lane] = s1[i];
    }
  }
}

// ================= k_mlp: radial MLP via MFMA, 16 edges/wave =================
template<int B>
__launch_bounds__(256)
__global__ void k_mlp(const float* __restrict__ er, const int* __restrict__ eidx,
                      const float* __restrict__ w0, const __hip_bfloat16* __restrict__ wpk,
                      __hip_bfloat16* __restrict__ wbuf, int ebase) {
  constexpr int NP = B ? 7 : 3;
  constexpr int NOC = NP * 4;
  __shared__ __align__(16) __hip_bfloat16 hsb[4][2][16][72];
  int wid = threadIdx.x >> 6, lane = threadIdx.x & 63;
  int g = blockIdx.x * 4 + wid;          // 16-edge group
  int base = ebase + g * 16;
  int col16 = lane & 15, kg = lane >> 4;

  int ev = (lane < 16) ? eidx[base + lane] : 0;

  // ---- layer 1: R=8 -> 64 (VALU, fp32 weights) ----
#pragma unroll 1
  for (int j = 0; j < 16; j++) {
    int e = __builtin_amdgcn_readlane(ev, j);
    float a = 0.f;
#pragma unroll
    for (int r = 0; r < 8; r++) a += er[e*8 + r] * w0[r*64 + lane];
    hsb[wid][0][j][lane] = __float2bfloat16(silu_f(a));
  }

  // ---- layers 2,3: 64->64 MFMA (src L, dst 1-L; wpk base L*4096) ----
#pragma unroll
  for (int L = 0; L < 2; L++) {
    const __hip_bfloat16* wp = wpk + L * 4096;
    bf16x8 A0 = *(const bf16x8*)&hsb[wid][L][col16][kg*8];
    bf16x8 A1 = *(const bf16x8*)&hsb[wid][L][col16][32 + kg*8];
    f32x4 acc[4];
#pragma unroll
    for (int oc = 0; oc < 4; oc++) acc[oc] = (f32x4){0.f,0.f,0.f,0.f};
#pragma unroll
    for (int ks = 0; ks < 2; ks++) {
      bf16x8 A = ks ? A1 : A0;
#pragma unroll
      for (int oc = 0; oc < 4; oc++) {
        bf16x8 Bf = *(const bf16x8*)&wp[((ks*4 + oc)*64 + lane)*8];
        acc[oc] = __builtin_amdgcn_mfma_f32_16x16x32_bf16(A, Bf, acc[oc], 0, 0, 0);
      }
    }
#pragma unroll
    for (int oc = 0; oc < 4; oc++)
#pragma unroll
      for (int i = 0; i < 4; i++)
        hsb[wid][1 - L][kg*4 + i][oc*16 + col16] = __float2bfloat16(silu_f(acc[oc][i]));
  }

  // ---- output layer: 64 -> NP*64 MFMA, serial col-tiles, stream to wbuf ----
  {
    bf16x8 A0 = *(const bf16x8*)&hsb[wid][0][col16][kg*8];
    bf16x8 A1 = *(const bf16x8*)&hsb[wid][0][col16][32 + kg*8];
    const __hip_bfloat16* wp = wpk + 8192;
#pragma unroll 1
    for (int oc = 0; oc < NOC; oc++) {
      f32x4 acc = (f32x4){0.f,0.f,0.f,0.f};
      bf16x8 B0 = *(const bf16x8*)&wp[((0*NOC + oc)*64 + lane)*8];
      bf16x8 B1 = *(const bf16x8*)&wp[((1*NOC + oc)*64 + lane)*8];
      acc = __builtin_amdgcn_mfma_f32_16x16x32_bf16(A0, B0, acc, 0, 0, 0);
      acc = __builtin_amdgcn_mfma_f32_16x16x32_bf16(A1, B1, acc, 0, 0, 0);
      int p = oc >> 2, chan = (oc & 3)*16 + col16;
#pragma unroll
      for (int i = 0; i < 4; i++) {
        int edge = kg*4 + i;
        wbuf[((size_t)(g*16 + edge) * NP + p)*64 + chan] = __float2bfloat16(acc[i]);
      }
    }
  }
}

// ================= k_tp: TP + receiver-run register-combine scatter =================
template<int B>
__launch_bounds__(256)
__global__ void k_tp(const float* __restrict__ esh,
                     const int* __restrict__ senders, const int* __restrict__ receivers,
                     const int* __restrict__ eidx,
                     const float* __restrict__ y0, const float* __restrict__ y1,
                     const __hip_bfloat16* __restrict__ wbuf, const float* __restrict__ cg,
                     float* __restrict__ Agg, int ebase) {
  constexpr int NP = B ? 7 : 3;
  constexpr int ROWS = B ? 21 : 9;
  constexpr int EPW = 32;
  __shared__ float cgs[363];
  int wid = threadIdx.x >> 6, lane = threadIdx.x & 63;
  for (int i = threadIdx.x; i < 363; i += 256) cgs[i] = cg[i];
  __syncthreads();

  int g = blockIdx.x * 4 + wid;
  int base = ebase + g * EPW;

  int ev = 0, rv = 0, sv = 0;
  if (lane < EPW) ev = eidx[base + lane];
  if (lane < EPW) { rv = receivers[ev]; sv = senders[ev]; }

  float acc[ROWS];
#pragma unroll
  for (int r = 0; r < ROWS; r++) acc[r] = 0.f;
  int rprev = -1;
#pragma unroll 1
  for (int j = 0; j < EPW; j++) {
    int e  = __builtin_amdgcn_readlane(ev, j);
    int r  = __builtin_amdgcn_readlane(rv, j);
    int sn = __builtin_amdgcn_readlane(sv, j);
    if (j > 0 && r != rprev) flush_acc<ROWS>(acc, Agg, rprev, lane);
    rprev = r;
    const __hip_bfloat16* wj = wbuf + ((size_t)(g*EPW + j)) * NP * 64 + lane;
    float w[NP];
#pragma unroll
    for (int p = 0; p < NP; p++) w[p] = __bfloat162float(wj[p*64]);
    float y0a[1] = { y0[sn*64 + lane] };
    float sh[9];
#pragma unroll
    for (int q = 0; q < 9; q++) sh[q] = esh[e*9 + q];
    if constexpr (B == 0) {
      tp_acc<1,1,1,0>(y0a, sh + 0, w[0], cgs, 0,  acc);
      tp_acc<1,3,3,1>(y0a, sh + 1, w[1], cgs, 1,  acc);
      tp_acc<1,5,5,4>(y0a, sh + 4, w[2], cgs, 10, acc);
    } else {
      tp_acc<1,1,1,0> (y0a, sh + 0, w[0], cgs, 0,  acc);
      tp_acc<1,3,3,2> (y0a, sh + 1, w[1], cgs, 1,  acc);
      tp_acc<1,5,5,11>(y0a, sh + 4, w[2], cgs, 10, acc);
      float y1a[3];
#pragma unroll
      for (int i = 0; i < 3; i++) y1a[i] = y1[(sn*3 + i)*64 + lane];
      tp_acc<3,1,3,5> (y1a, sh + 0, w[3], cgs, 35, acc);
      tp_acc<3,3,1,1> (y1a, sh + 1, w[4], cgs, 44, acc);
      tp_acc<3,3,5,16>(y1a, sh + 1, w[5], cgs, 53, acc);
      tp_acc<3,5,3,8> (y1a, sh + 4, w[6], cgs, 98, acc);
    }
  }
  flush_acc<ROWS>(acc, Agg, rprev, lane);
}

// ================= k_lin: A = lin(Agg) via MFMA, in place =================
template<int D, int KS>
__device__ __forceinline__ void lin_phase(const float* __restrict__ anA, int rowsx64_unused,
                                          const __hip_bfloat16* __restrict__ wp,
                                          int oc, int lane, int inbase, int stride64,
                                          f32x4 (&acc)[D]) {
#pragma unroll
  for (int i = 0; i < D; i++) {
    f32x4 a = (f32x4){0.f,0.f,0.f,0.f};
#pragma unroll
    for (int ks = 0; ks < KS; ks++) {
      int kglob = ks*32 + ((lane >> 4) * 8);
      int P = kglob >> 6, ch = kglob & 63;
      bf16x8 A = cvt8(anA + (inbase + P*stride64 + i)*64 + ch);
      bf16x8 Bf = *(const bf16x8*)&wp[((ks*4 + oc)*64 + lane)*8];
      a = __builtin_amdgcn_mfma_f32_16x16x32_bf16(A, Bf, a, 0, 0, 0);
    }
    acc[i] = a;
  }
}

template<int B>
__launch_bounds__(256)
__global__ void k_lin(float* __restrict__ Agg, const __hip_bfloat16* __restrict__ wlpk) {
  constexpr int P0 = B ? 2 : 1, P1 = B ? 3 : 1, P2 = B ? 2 : 1;
  constexpr int ROWS = P0 + 3*P1 + 5*P2;
  constexpr int BASE1 = P0, BASE2 = P0 + 3*P1;
  constexpr int KS0 = P0*2, KS1 = P1*2, KS2 = P2*2;
  constexpr int OFF1 = KS0*2048, OFF2 = OFF1 + KS1*2048;
  int wid = threadIdx.x >> 6, lane = threadIdx.x & 63;
  int oc = wid;
  int n0 = blockIdx.x * 16;
  int m = lane & 15;
  const float* anA = Agg + (size_t)(n0 + m) * (ROWS*64);

  f32x4 a0[1], a1[3], a2[5];
  lin_phase<1, KS0>(anA, 0, wlpk,        oc, lane, 0,     1, a0);
  lin_phase<3, KS1>(anA, 0, wlpk + OFF1, oc, lane, BASE1, 3, a1);
  lin_phase<5, KS2>(anA, 0, wlpk + OFF2, oc, lane, BASE2, 5, a2);

  __syncthreads();   // all reads in block done before any write

  int col = oc*16 + (lane & 15);
  int kg = lane >> 4;
#pragma unroll
  for (int r = 0; r < 4; r++) {
    float* an = Agg + (size_t)(n0 + kg*4 + r) * (ROWS*64);
    an[0*64 + col] = a0[0][r];
#pragma unroll
    for (int i = 0; i < 3; i++) an[(1 + i)*64 + col] = a1[i][r];
#pragma unroll
    for (int i = 0; i < 5; i++) an[(4 + i)*64 + col] = a2[i][r];
  }
}

// ================= node post, phase 2+3 fused: product basis + out GEMV =================
// Round-18 configuration (measured 91us, VGPR 212, no spill): all weights
// LDS-staged, it-loop fully unrolled. Round-20's unroll-1 + de-staging
// variant spilled (VGPR 256, FETCH 199MB) -- do not repeat.
template<int B>
__launch_bounds__(256)
__global__ void k_pbout(const float* __restrict__ Agg, const int* __restrict__ elem,
                        const float* __restrict__ w2p, const float* __restrict__ w3p,
                        const float* __restrict__ wnu, const float* __restrict__ cg,
                        const float* __restrict__ plin0, const float* __restrict__ plin1,
                        const float* __restrict__ sc0, const float* __restrict__ sc1,
                        float* __restrict__ x0n, float* __restrict__ x1n,
                        float* __restrict__ out, int obase, int npb) {
  constexpr int ROWS = B ? 21 : 9;
  __shared__ float cgs[363];
  __shared__ float w2s[4*11*64];
  __shared__ float w3s[4*11*64];
  __shared__ float wns[4*3*2*64];
  __shared__ float p0s[64*64];
  __shared__ float p1s[64*64];
  __shared__ float Bs[4][4][64];
  int wid = threadIdx.x >> 6, lane = threadIdx.x & 63;
  for (int i = threadIdx.x; i < 363; i += 256) cgs[i] = cg[i];
  for (int i = threadIdx.x; i < 4*11*64; i += 256) { w2s[i] = w2p[i]; w3s[i] = w3p[i]; }
  for (int i = threadIdx.x; i < 4*3*2*64; i += 256) wns[i] = wnu[i];
  for (int i = threadIdx.x; i < 64*64; i += 256) { p0s[i] = plin0[i]; p1s[i] = plin1[i]; }
  __syncthreads();

  int n0 = blockIdx.x * npb;
  int nend = n0 + npb; if (nend > NNODES) nend = NNODES;
  for (int n = n0 + wid; n < nend; n += 4) {
    int z = elem[n];
    const float* an = Agg + (size_t)n * (ROWS*64);
    float A0[1] = { an[0*64 + lane] };
    float A1[3], A2[5];
#pragma unroll
    for (int i = 0; i < 3; i++) A1[i] = an[(1 + i)*64 + lane];
#pragma unroll
    for (int i = 0; i < 5; i++) A2[i] = an[(4 + i)*64 + lane];

    float T0[1] = {A0[0]};
    float T1[3], T2[5];
#pragma unroll
    for (int i = 0; i < 3; i++) T1[i] = A1[i];
#pragma unroll
    for (int i = 0; i < 5; i++) T2[i] = A2[i];
    float s10 = 0.f, s11[3] = {0.f,0.f,0.f}, s20 = 0.f, s21[3] = {0.f,0.f,0.f};
#pragma unroll
    for (int it = 0; it < 2; it++) {
      const float* wp = it ? w3s : w2s;
      float c[11];
#pragma unroll
      for (int p = 0; p < 11; p++) c[p] = wp[(z*11 + p)*64 + lane];
      float n0v[1] = {0.f}, n1v[3] = {0.f,0.f,0.f}, n2v[5] = {0.f,0.f,0.f,0.f,0.f};
      pb_path<1,1,1>(c[0],  T0, A0, n0v, cgs, 0);
      pb_path<1,3,3>(c[1],  T0, A1, n1v, cgs, 1);
      pb_path<1,5,5>(c[2],  T0, A2, n2v, cgs, 10);
      pb_path<3,1,3>(c[3],  T1, A0, n1v, cgs, 35);
      pb_path<3,3,1>(c[4],  T1, A1, n0v, cgs, 44);
      pb_path<3,3,5>(c[5],  T1, A1, n2v, cgs, 53);
      pb_path<3,5,3>(c[6],  T1, A2, n1v, cgs, 98);
      pb_path<5,1,5>(c[7],  T2, A0, n2v, cgs, 143);
      pb_path<5,3,3>(c[8],  T2, A1, n1v, cgs, 168);
      pb_path<5,5,1>(c[9],  T2, A2, n0v, cgs, 213);
      pb_path<5,5,5>(c[10], T2, A2, n2v, cgs, 238);
      T0[0] = n0v[0];
#pragma unroll
      for (int i = 0; i < 3; i++) T1[i] = n1v[i];
#pragma unroll
      for (int i = 0; i < 5; i++) T2[i] = n2v[i];
      if (it == 0) {
        s10 = n0v[0];
#pragma unroll
        for (int i = 0; i < 3; i++) s11[i] = n1v[i];
      } else {
        s20 = n0v[0];
#pragma unroll
        for (int i = 0; i < 3; i++) s21[i] = n1v[i];
      }
    }

    float c00 = wns[((z*3 + 0)*2 + 0)*64 + lane];
    float c10 = wns[((z*3 + 1)*2 + 0)*64 + lane];
    float c20 = wns[((z*3 + 2)*2 + 0)*64 + lane];
    float c01 = wns[((z*3 + 0)*2 + 1)*64 + lane];
    float c11 = wns[((z*3 + 1)*2 + 1)*64 + lane];
    float c21 = wns[((z*3 + 2)*2 + 1)*64 + lane];
    Bs[wid][0][lane] = c00*A0[0] + c10*s10 + c20*s20;
#pragma unroll
    for (int i = 0; i < 3; i++)
      Bs[wid][1 + i][lane] = c01*A1[i] + c11*s11[i] + c21*s21[i];
    // same wave consumes Bs (within-wave LDS RAW order) -> no barrier

    float x0v = 0.f, x1v[3] = {0.f,0.f,0.f};
    for (int k = 0; k < 64; k++) {
      float p0v = p0s[k*64 + lane];
      float p1v = p1s[k*64 + lane];
      x0v += Bs[wid][0][k] * p0v;
#pragma unroll
      for (int i = 0; i < 3; i++) x1v[i] += Bs[wid][1 + i][k] * p1v;
    }
    x0v += sc0[n*64 + lane];
    if (B) {
#pragma unroll
      for (int i = 0; i < 3; i++) x1v[i] += sc1[(n*3 + i)*64 + lane];
    }
    if (B == 0) {
      x0n[n*64 + lane] = x0v;
#pragma unroll
      for (int i = 0; i < 3; i++) x1n[(n*3 + i)*64 + lane] = x1v[i];
    }
    out[(size_t)n*512 + obase + lane] = x0v;
#pragma unroll
    for (int i = 0; i < 3; i++)
      out[(size_t)n*512 + obase + 64 + lane*3 + i] = x1v[i];
  }
}

// ================= launch =================
extern "C" void kernel_launch(void* const* d_in, const int* in_sizes, int n_in,
                              void* d_out, int out_size, void* d_ws, size_t ws_size,
                              hipStream_t stream) {
  const float* node_feats  = (const float*)d_in[0];
  const int*   node_elem   = (const int*)  d_in[1];
  const float* edge_sh     = (const float*)d_in[2];
  const float* edge_radial = (const float*)d_in[3];
  const int*   senders     = (const int*)  d_in[4];
  const int*   receivers   = (const int*)  d_in[5];
  const float* up0_l0   = (const float*)d_in[6];
  const float* r0_w0    = (const float*)d_in[7];
  const float* r0_w1    = (const float*)d_in[8];
  const float* r0_w2    = (const float*)d_in[9];
  const float* r0_wo    = (const float*)d_in[10];
  const float* lin0_l0  = (const float*)d_in[11];
  const float* lin0_l1  = (const float*)d_in[12];
  const float* lin0_l2  = (const float*)d_in[13];
  const float* sc0_l0   = (const float*)d_in[14];
  const float* p0_w2    = (const float*)d_in[15];
  const float* p0_w3    = (const float*)d_in[16];
  const float* p0_wnu   = (const float*)d_in[17];
  const float* p0_lin_l0= (const float*)d_in[18];
  const float* p0_lin_l1= (const float*)d_in[19];
  const float* up1_l0   = (const float*)d_in[20];
  const float* up1_l1   = (const float*)d_in[21];
  const float* r1_w0    = (const float*)d_in[22];
  const float* r1_w1    = (const float*)d_in[23];
  const float* r1_w2    = (const float*)d_in[24];
  const float* r1_wo    = (const float*)d_in[25];
  const float* lin1_l0  = (const float*)d_in[26];
  const float* lin1_l1  = (const float*)d_in[27];
  const float* lin1_l2  = (const float*)d_in[28];
  const float* sc1_l0   = (const float*)d_in[29];
  const float* sc1_l1   = (const float*)d_in[30];
  const float* p1_w2    = (const float*)d_in[31];
  const float* p1_w3    = (const float*)d_in[32];
  const float* p1_wnu   = (const float*)d_in[33];
  const float* p1_lin_l0= (const float*)d_in[34];
  const float* p1_lin_l1= (const float*)d_in[35];

  float* ws  = (float*)d_ws;
  float* cg  = ws + WS_CG;
  float* y0  = ws + WS_Y0;
  float* y1  = ws + WS_Y1;
  float* sc0 = ws + WS_SC0;
  float* sc1 = ws + WS_SC1;
  float* x0n = ws + WS_X0N;
  float* x1n = ws + WS_X1N;
  float* Agg = ws + WS_AGG;
  int* counts = (int*)(ws + WS_CSR);
  int* off    = counts + NNODES;       // NNODES+1
  int* cursor = off + NNODES + 1;      // NNODES
  int* eidx   = cursor + NNODES;       // NEDGES
  __hip_bfloat16* wpk  = (__hip_bfloat16*)(ws + WS_WPK);
  __hip_bfloat16* wlpk = (__hip_bfloat16*)(ws + WS_WLPK);
  __hip_bfloat16* wbuf = (__hip_bfloat16*)(ws + WS_WBUF);
  float* out = (float*)d_out;

  // chunk size from available workspace (bf16 rows of 7*64 elems, 128-edge aligned)
  size_t cap_bytes = (ws_size > (size_t)WS_WBUF*4) ? ws_size - (size_t)WS_WBUF*4 : 0;
  int chunk = 131072;
  if (cap_bytes < (size_t)chunk * 7 * 64 * 2) {
    chunk = (int)((cap_bytes / (7*64*2)) & ~(size_t)127);
    if (chunk < 128) chunk = 128;
  }
  const int NPB = 32;                       // nodes per k_pbout block
  const int NODE_BLOCKS = (NNODES + NPB - 1) / NPB;

  k_cg<<<1, 512, 0, stream>>>(cg);

  // ---- CSR/sort build (shared by both blocks) ----
  hipMemsetAsync(counts, 0, NNODES * sizeof(int), stream);
  k_hist<<<(NEDGES + 255) / 256, 256, 0, stream>>>(receivers, counts);
  k_scan<<<1, 256, 0, stream>>>(counts, off, cursor);
  k_bucket<<<(NEDGES + 255) / 256, 256, 0, stream>>>(receivers, cursor, eidx);

  // ---- interaction block 0 ----
  k_node_pre<0><<<NNODES/4, 256, 0, stream>>>(node_feats, nullptr, node_elem,
                                              up0_l0, nullptr, sc0_l0, nullptr,
                                              y0, y1, sc0, sc1);
  hipMemsetAsync(Agg, 0, (size_t)NNODES * 9 * 64 * sizeof(float), stream);
  k_wprep<0><<<(8192 + 2*3*4*512 + 255)/256, 256, 0, stream>>>(r0_w1, r0_w2, r0_wo, wpk);
  k_linprep<0><<<(6*2048 + 255)/256, 256, 0, stream>>>(lin0_l0, lin0_l1, lin0_l2, wlpk);
  for (int e0 = 0; e0 < NEDGES; e0 += chunk) {
    int ce = (NEDGES - e0 < chunk) ? (NEDGES - e0) : chunk;
    k_mlp<0><<<ce/64, 256, 0, stream>>>(edge_radial, eidx, r0_w0, wpk, wbuf, e0);
    k_tp<0><<<ce/128, 256, 0, stream>>>(edge_sh, senders, receivers, eidx, y0, y1, wbuf, cg, Agg, e0);
  }
  k_lin<0><<<NNODES/16, 256, 0, stream>>>(Agg, wlpk);
  k_pbout<0><<<NODE_BLOCKS, 256, 0, stream>>>(Agg, node_elem, p0_w2, p0_w3, p0_wnu, cg,
                                              p0_lin_l0, p0_lin_l1, sc0, sc1,
                                              x0n, x1n, out, 0, NPB);

  // ---- interaction block 1 ----
  k_node_pre<1><<<NNODES/4, 256, 0, stream>>>(x0n, x1n, node_elem,
                                              up1_l0, up1_l1, sc1_l0, sc1_l1,
                                              y0, y1, sc0, sc1);
  hipMemsetAsync(Agg, 0, (size_t)NNODES * 21 * 64 * sizeof(float), stream);
  k_wprep<1><<<(8192 + 2*7*4*512 + 255)/256, 256, 0, stream>>>(r1_w1, r1_w2, r1_wo, wpk);
  k_linprep<1><<<(14*2048 + 255)/256, 256, 0, stream>>>(lin1_l0, lin1_l1, lin1_l2, wlpk);
  for (int e0 = 0; e0 < NEDGES; e0 += chunk) {
    int ce = (NEDGES - e0 < chunk) ? (NEDGES - e0) : chunk;
    k_mlp<1><<<ce/64, 256, 0, stream>>>(edge_radial, eidx, r1_w0, wpk, wbuf, e0);
    k_tp<1><<<ce/128, 256, 0, stream>>>(edge_sh, senders, receivers, eidx, y0, y1, wbuf, cg, Agg, e0);
  }
  k_lin<1><<<NNODES/16, 256, 0, stream>>>(Agg, wlpk);
  k_pbout<1><<<NODE_BLOCKS, 256, 0, stream>>>(Agg, node_elem, p1_w2, p1_w3, p1_wnu, cg,
                                              p1_lin_l0, p1_lin_l1, sc0, sc1,
                                              x0n, x1n, out, 256, NPB);
}